// Round 1
// 511.129 us; speedup vs baseline: 1.1193x; 1.1193x over previous
//
#include <hip/hip_runtime.h>
#include <stdint.h>

// ---------------------------------------------------------------------------
// SpikeMLP (all fp32 I/O):
//   h = x @ w1^T            (16384,512)x(2048,512)^T -> (16384,2048)
//   spikes,rate = LIF(h)    scan over t (4 steps, rows grouped (b,t,s))
//   out = spikes @ w2^T     (16384,2048)x(512,2048)^T -> (16384,512)
//
// Numerics contract (established round 3, DO NOT BREAK):
//   - GEMM1 (k1): per-element f32 sequential FMA over k=0..511 ascending,
//     one accumulator -> bit-exact match of the np reference's h.
//   - LIF: vv = __fmul_rn(0.95f, v); vv = __fadd_rn(vv, h); spike = vv > 1.
//   - GEMM2 is continuous in spikes {0,1} -> MFMA allowed (w2 hi+lo bf16).
//
// k1 (round 8 redesign for occupancy):
//   Tile 128x128 (rows = 4t x 32s, b fixed), 256 thr, 8x8 micro -> acc=64
//   VGPR/thread, __launch_bounds__(256,4) -> 4 waves/SIMD (was 2).
//   Row permutation p = sl*4 + t: each thread owns 2 s-values x all 4 t
//   -> LIF t-chain is thread-local, NO shfl epilogue.
//   LDS: k-major with ADDITIVE skew, slot = p + 16*(k>>2), stride 176
//   (22.5 KB total). All inner-loop ds_read addresses = thread base +
//   compile-time immediate (k fully unrolled) -> ~zero per-k VALU addr math.
//   Bank audit: A-reads 16-lane broadcast at 4 disjoint quads (free);
//   B-reads 2-way (free, m136); stage writes exactly 2-way (free).
//   Global stage loads issued BEFORE the first barrier (no LDS dep) so HBM
//   latency overlaps the previous chunk's compute.
// ---------------------------------------------------------------------------

typedef __attribute__((ext_vector_type(8))) short short8;   // 8 bf16 = 16 B
typedef __attribute__((ext_vector_type(4))) float f32x4;

#define AS1 __attribute__((address_space(1)))
#define AS3 __attribute__((address_space(3)))

__device__ __forceinline__ void load_lds16(const void* g, void* l) {
  __builtin_amdgcn_global_load_lds((const AS1 void*)g, (AS3 void*)l, 16, 0, 0);
}

__device__ __forceinline__ unsigned short f2bf(float f) {
  union { float f; unsigned u; } un; un.f = f;
  unsigned r = un.u + 0x7FFF + ((un.u >> 16) & 1);   // RNE
  return (unsigned short)(r >> 16);
}
__device__ __forceinline__ float bf2f(unsigned short u) {
  union { unsigned u; float f; } un; un.u = ((unsigned)u) << 16; return un.f;
}

// ---------------------------------------------------------------------------
// K0: split w2 (fp32) into bf16 hi + lo.
// ---------------------------------------------------------------------------
__global__ __launch_bounds__(256) void k0_split(
    const float* __restrict__ w2, unsigned short* __restrict__ hi,
    unsigned short* __restrict__ lo)
{
  int i = (blockIdx.x * 256 + threadIdx.x) * 4;
  float4 w = *(const float4*)&w2[i];
  unsigned short h4[4], l4[4];
  float ws[4] = {w.x, w.y, w.z, w.w};
#pragma unroll
  for (int c = 0; c < 4; ++c) {
    unsigned short h = f2bf(ws[c]);
    h4[c] = h;
    l4[c] = f2bf(ws[c] - bf2f(h));
  }
  *(ushort4*)&hi[i] = *(const ushort4*)h4;
  *(ushort4*)&lo[i] = *(const ushort4*)l4;
}

// ---------------------------------------------------------------------------
// K1: fused GEMM1 (f32 seq-FMA, bit-exact) + thread-local LIF epilogue.
// Block tile: 128 rows (4t x 32s, permuted p = sl*4+t) x 128 cols.
// 256 threads, 8x8 micro. Grid (128, 16): bx -> (b = bx>>3, s0 = (bx&7)*32);
// by -> h0 = by*128.
// ---------------------------------------------------------------------------
#define K1KT 16
#define SA_STR 176   // 128 slots + 48 skew; skew = 16*(k>>2)
#define SB_STR 176

__global__ __launch_bounds__(256, 4) void k1_gemm_lif(
    const float* __restrict__ x,          // (16384, 512), row=((b*4+t)*256+s)
    const float* __restrict__ w1,         // (2048, 512)
    unsigned short* __restrict__ spikes,  // (16384, 2048) bf16 {0,1}
    unsigned* __restrict__ cnt_out)
{
  __shared__ float sA[K1KT * SA_STR];   // 11.0 KB
  __shared__ float sB[K1KT * SB_STR];   // 11.0 KB

  const int tid = threadIdx.x;
  const int tx  = tid & 15;    // col group: cols tx*4..+3 and 64+tx*4..+3
  const int ty  = tid >> 4;    // s-pair index: sl = ty*2 + i, i in {0,1}

  const int bx = blockIdx.x;
  const int b  = bx >> 3;
  const int s0 = (bx & 7) * 32;
  const int h0 = blockIdx.y * 128;

  const int kg = tid & 3;      // staging k-group (kg*4 .. +3 within chunk)
  const int u  = tid >> 2;     // staging slot 0..63 (p = u and u+64)

  float acc[8][8];             // acc[m][j], m = i*4 + t
#pragma unroll
  for (int m = 0; m < 8; ++m)
#pragma unroll
    for (int j = 0; j < 8; ++j) acc[m][j] = 0.0f;

  // Staging global sources. p = u (+64): t = p&3 (64%4==0 -> same t), sl=p>>2.
  const size_t growA0 = ((size_t)(b * 4 + (u & 3)) << 8) + s0 + (u >> 2);
  const size_t growA1 = growA0 + 16;                       // p = u+64: sl += 16
  const float* xA0 = x  + growA0 * 512 + kg * 4;
  const float* xA1 = x  + growA1 * 512 + kg * 4;
  const float* wB0 = w1 + (size_t)(h0 + u) * 512 + kg * 4;
  const float* wB1 = w1 + (size_t)(h0 + u + 64) * 512 + kg * 4;

  // Staging LDS destinations: element (p, k=4*kg+c) -> [k*STR + p + 16*kg].
  float* sAw = &sA[(4 * kg) * SA_STR + u + 16 * kg];   // + c*SA_STR + 64*j imm
  float* sBw = &sB[(4 * kg) * SB_STR + u + 16 * kg];

  // Read bases: all per-k offsets are compile-time immediates.
  const float* sAr = &sA[ty * 8];
  const float* sBr = &sB[tx * 4];

  for (int k0 = 0; k0 < 512; k0 += K1KT) {
    // global loads first: no LDS dependency -> overlap prev chunk's compute
    float4 a0v = *(const float4*)(xA0 + k0);
    float4 a1v = *(const float4*)(xA1 + k0);
    float4 b0v = *(const float4*)(wB0 + k0);
    float4 b1v = *(const float4*)(wB1 + k0);

    __syncthreads();  // protect LDS from previous chunk's readers
    {
      float a0s[4] = {a0v.x, a0v.y, a0v.z, a0v.w};
      float a1s[4] = {a1v.x, a1v.y, a1v.z, a1v.w};
      float b0s[4] = {b0v.x, b0v.y, b0v.z, b0v.w};
      float b1s[4] = {b1v.x, b1v.y, b1v.z, b1v.w};
#pragma unroll
      for (int c = 0; c < 4; ++c) {
        sAw[c * SA_STR]      = a0s[c];
        sAw[c * SA_STR + 64] = a1s[c];
        sBw[c * SB_STR]      = b0s[c];
        sBw[c * SB_STR + 64] = b1s[c];
      }
    }
    __syncthreads();

#pragma unroll
    for (int k = 0; k < K1KT; ++k) {
      const int off = k * SA_STR + 16 * (k >> 2);   // compile-time
      float4 va0 = *(const float4*)(sAr + off);      // rows p0..p0+3 (i=0)
      float4 va1 = *(const float4*)(sAr + off + 4);  // rows p0+4..p0+7 (i=1)
      float4 vb0 = *(const float4*)(sBr + off);      // cols tx*4..+3
      float4 vb1 = *(const float4*)(sBr + off + 64); // cols 64+tx*4..+3
      float av[8] = {va0.x, va0.y, va0.z, va0.w, va1.x, va1.y, va1.z, va1.w};
      float bv[8] = {vb0.x, vb0.y, vb0.z, vb0.w, vb1.x, vb1.y, vb1.z, vb1.w};
#pragma unroll
      for (int m = 0; m < 8; ++m)
#pragma unroll
        for (int j = 0; j < 8; ++j)
          acc[m][j] = __builtin_fmaf(av[m], bv[j], acc[m][j]);
    }
  }

  // Epilogue: LIF. Thread owns all 4 t of its 2 s-rows -> local chain.
  unsigned cnt = 0;
#pragma unroll
  for (int i = 0; i < 2; ++i) {
    unsigned short sp[4][8];
#pragma unroll
    for (int j = 0; j < 8; ++j) {
      float v = 0.0f;
#pragma unroll
      for (int t = 0; t < 4; ++t) {
        float vv = __fadd_rn(__fmul_rn(0.95f, v), acc[i * 4 + t][j]);
        bool s = vv > 1.0f;                 // numpy op-for-op
        sp[t][j] = s ? (unsigned short)0x3F80 : (unsigned short)0;
        cnt += s ? 1u : 0u;
        v = s ? 0.0f : vv;
      }
    }
#pragma unroll
    for (int t = 0; t < 4; ++t) {
      size_t grow = ((size_t)(b * 4 + t) << 8) + s0 + ty * 2 + i;
      unsigned short* rowp = spikes + grow * 2048 + h0;
      ushort4 o0, o1;
      o0.x = sp[t][0]; o0.y = sp[t][1]; o0.z = sp[t][2]; o0.w = sp[t][3];
      o1.x = sp[t][4]; o1.y = sp[t][5]; o1.z = sp[t][6]; o1.w = sp[t][7];
      *(ushort4*)&rowp[tx * 4]      = o0;
      *(ushort4*)&rowp[64 + tx * 4] = o1;
    }
  }

  // wave-reduce spike count -> one atomic per wave
#pragma unroll
  for (int off = 32; off; off >>= 1) cnt += __shfl_down(cnt, off);
  if ((tid & 63) == 0) atomicAdd(cnt_out, cnt);
}

// ---------------------------------------------------------------------------
// K2: out = spikes @ (w2_hi + w2_lo)^T via bf16 MFMA, fp32 accum.
// 128x128 tile, BK=64, global_load_lds w=16, XOR swizzle. Grid (128, 4).
// ---------------------------------------------------------------------------
__global__ __launch_bounds__(256, 2) void k2_gemm_mfma(
    const unsigned short* __restrict__ spikes,  // (16384, 2048) bf16
    const unsigned short* __restrict__ w2h,     // (512, 2048) bf16
    const unsigned short* __restrict__ w2l,     // (512, 2048) bf16
    float* __restrict__ out)                    // (16384, 512) fp32
{
  __shared__ alignas(16) short smA [128 * 64];
  __shared__ alignas(16) short smBh[128 * 64];
  __shared__ alignas(16) short smBl[128 * 64];

  const int tid  = threadIdx.x;
  const int lane = tid & 63;
  const int quad = lane >> 4;
  const int l15  = lane & 15;
  const int wv   = tid >> 6;
  const int wm   = wv & 1;
  const int wn   = wv >> 1;

  const size_t r0 = (size_t)blockIdx.x * 128;
  const int    d0 = blockIdx.y * 128;

  int srow[4], sg8[4];
#pragma unroll
  for (int j = 0; j < 4; ++j) {
    int gi  = j * 256 + tid;
    srow[j] = gi >> 3;
    sg8[j]  = ((gi & 7) ^ (srow[j] & 7)) * 8;
  }

  const unsigned short* ab  = spikes + r0 * 2048;
  const unsigned short* bhb = w2h + (size_t)d0 * 2048;
  const unsigned short* blb = w2l + (size_t)d0 * 2048;

  f32x4 acc[4][4] = {};

  for (int k0 = 0; k0 < 2048; k0 += 64) {
    __syncthreads();
#pragma unroll
    for (int j = 0; j < 4; ++j) {
      load_lds16(ab  + (size_t)srow[j] * 2048 + k0 + sg8[j],
                 &smA [(j * 256 + tid) * 8]);
      load_lds16(bhb + (size_t)srow[j] * 2048 + k0 + sg8[j],
                 &smBh[(j * 256 + tid) * 8]);
      load_lds16(blb + (size_t)srow[j] * 2048 + k0 + sg8[j],
                 &smBl[(j * 256 + tid) * 8]);
    }
    __syncthreads();

#pragma unroll
    for (int ks = 0; ks < 2; ++ks) {
      short8 af[4], bh[4], bl[4];
#pragma unroll
      for (int mi = 0; mi < 4; ++mi) {
        int m = wm * 64 + mi * 16 + l15;
        af[mi] = ((const short8*)smA)[m * 8 + ((ks * 4 + quad) ^ (m & 7))];
      }
#pragma unroll
      for (int ni = 0; ni < 4; ++ni) {
        int n = wn * 64 + ni * 16 + l15;
        int sl = n * 8 + ((ks * 4 + quad) ^ (n & 7));
        bh[ni] = ((const short8*)smBh)[sl];
        bl[ni] = ((const short8*)smBl)[sl];
      }
#pragma unroll
      for (int mi = 0; mi < 4; ++mi)
#pragma unroll
        for (int ni = 0; ni < 4; ++ni) {
          acc[mi][ni] = __builtin_amdgcn_mfma_f32_16x16x32_bf16(
              af[mi], bh[ni], acc[mi][ni], 0, 0, 0);
          acc[mi][ni] = __builtin_amdgcn_mfma_f32_16x16x32_bf16(
              af[mi], bl[ni], acc[mi][ni], 0, 0, 0);
        }
    }
  }

  float* ob = out + r0 * 512 + d0;
#pragma unroll
  for (int mi = 0; mi < 4; ++mi)
#pragma unroll
    for (int ni = 0; ni < 4; ++ni)
#pragma unroll
      for (int r = 0; r < 4; ++r) {
        int rr = wm * 64 + mi * 16 + quad * 4 + r;   // C/D: row=quad*4+reg
        int cc = wn * 64 + ni * 16 + l15;            //      col=lane&15
        ob[(size_t)rr * 512 + cc] = acc[mi][ni][r];
      }
}

// ---------------------------------------------------------------------------
// K2 fallback (no extra ws): out = spikes @ w2^T, fp32 VALU. Grid (256, 8).
// ---------------------------------------------------------------------------
#define KT 16
#define PADF 68

__global__ __launch_bounds__(256) void k2_gemm_valu(
    const unsigned short* __restrict__ spikes,
    const float* __restrict__ w2,
    float* __restrict__ out)
{
  __shared__ float sA[KT][PADF];
  __shared__ float sB[KT][PADF];

  const int tid = threadIdx.x;
  const int tx  = tid & 15;
  const int ty  = tid >> 4;
  const int lr  = tid >> 2;
  const int lg  = tid & 3;

  const size_t r0 = (size_t)blockIdx.x * 64;
  const int    d0 = blockIdx.y * 64;

  float acc[4][4];
#pragma unroll
  for (int i = 0; i < 4; ++i)
#pragma unroll
    for (int j = 0; j < 4; ++j) acc[i][j] = 0.0f;

  for (int k0 = 0; k0 < 2048; k0 += KT) {
    __syncthreads();
    ushort4 av = *(const ushort4*)&spikes[(r0 + lr) * 2048 + k0 + lg * 4];
    float4  bv = *(const float4*)&w2[(size_t)(d0 + lr) * 2048 + k0 + lg * 4];
    sA[lg * 4 + 0][lr] = bf2f(av.x); sA[lg * 4 + 1][lr] = bf2f(av.y);
    sA[lg * 4 + 2][lr] = bf2f(av.z); sA[lg * 4 + 3][lr] = bf2f(av.w);
    sB[lg * 4 + 0][lr] = bv.x; sB[lg * 4 + 1][lr] = bv.y;
    sB[lg * 4 + 2][lr] = bv.z; sB[lg * 4 + 3][lr] = bv.w;
    __syncthreads();

#pragma unroll
    for (int k = 0; k < KT; ++k) {
      float4 a4 = *(const float4*)&sA[k][ty * 4];
      float4 b4 = *(const float4*)&sB[k][tx * 4];
      float aa[4] = {a4.x, a4.y, a4.z, a4.w};
      float bb[4] = {b4.x, b4.y, b4.z, b4.w};
#pragma unroll
      for (int i = 0; i < 4; ++i)
#pragma unroll
        for (int j = 0; j < 4; ++j)
          acc[i][j] = __builtin_fmaf(aa[i], bb[j], acc[i][j]);
    }
  }

#pragma unroll
  for (int i = 0; i < 4; ++i) {
    float4 o = make_float4(acc[i][0], acc[i][1], acc[i][2], acc[i][3]);
    *(float4*)&out[(r0 + ty * 4 + i) * 512 + d0 + tx * 4] = o;
  }
}

// ---------------------------------------------------------------------------
// K3: rate = count / 33554432 -> fp32 at d_out[8388608]
// ---------------------------------------------------------------------------
__global__ void k3_rate(const unsigned* __restrict__ cnt, float* __restrict__ dst) {
  dst[0] = (float)((double)(*cnt) / 33554432.0);
}

extern "C" void kernel_launch(void* const* d_in, const int* in_sizes, int n_in,
                              void* d_out, int out_size, void* d_ws, size_t ws_size,
                              hipStream_t stream) {
  const float* x  = (const float*)d_in[0];
  const float* w1 = (const float*)d_in[1];
  const float* w2 = (const float*)d_in[2];
  float* out = (float*)d_out;

  unsigned* cnt = (unsigned*)d_ws;
  unsigned short* spikes = (unsigned short*)((char*)d_ws + 256);
  const size_t SPIKES_B = (size_t)16384 * 2048 * 2;           // 67108864
  unsigned short* w2h = (unsigned short*)((char*)d_ws + 256 + SPIKES_B);
  unsigned short* w2l = w2h + (size_t)512 * 2048;
  const size_t NEED_SPLIT = 256 + SPIKES_B + 2 * (size_t)512 * 2048 * 2;

  hipMemsetAsync(d_ws, 0, 256, stream);  // zero the spike counter

  hipLaunchKernelGGL(k1_gemm_lif, dim3(128, 16), dim3(256), 0, stream,
                     x, w1, spikes, cnt);

  if (ws_size >= NEED_SPLIT) {
    hipLaunchKernelGGL(k0_split, dim3(1024), dim3(256), 0, stream, w2, w2h, w2l);
    hipLaunchKernelGGL(k2_gemm_mfma, dim3(128, 4), dim3(256), 0, stream,
                       spikes, w2h, w2l, out);
  } else {
    hipLaunchKernelGGL(k2_gemm_valu, dim3(256, 8), dim3(256), 0, stream,
                       spikes, w2, out);
  }

  hipLaunchKernelGGL(k3_rate, dim3(1), dim3(1), 0, stream, cnt, out + 8388608);
}